// Round 6
// baseline (91.110 us; speedup 1.0000x reference)
//
#include <hip/hip_runtime.h>
#include <math.h>

#define K_DIM 64
#define DEG 32

// Sum across all 64 lanes of the wave; every lane gets the result.
__device__ __forceinline__ float wave_sum(float v) {
    #pragma unroll
    for (int off = 32; off > 0; off >>= 1)
        v += __shfl_xor(v, off, 64);
    return v;
}

// Sum across each 16-lane row-group using DPP row_ror (pure VALU).
__device__ __forceinline__ float group16_sum(float v) {
    int x;
    x = __builtin_amdgcn_update_dpp(0, __float_as_int(v), 0x121, 0xf, 0xf, true);
    v += __int_as_float(x);
    x = __builtin_amdgcn_update_dpp(0, __float_as_int(v), 0x122, 0xf, 0xf, true);
    v += __int_as_float(x);
    x = __builtin_amdgcn_update_dpp(0, __float_as_int(v), 0x124, 0xf, 0xf, true);
    v += __int_as_float(x);
    x = __builtin_amdgcn_update_dpp(0, __float_as_int(v), 0x128, 0xf, 0xf, true);
    v += __int_as_float(x);
    return v;
}

// nn.Embedding(max_norm=1): scale = min(1, 1/max(||e||,1e-12)).
__device__ __forceinline__ float renorm_scale(float n2) {
    return fminf(1.0f, __frsqrt_rn(n2));
}

// Zero bitmap + live counter.
__global__ void gafm_bitmap_zero(unsigned int* __restrict__ bitmap, int n_words,
                                 int* __restrict__ live_count) {
    int i = blockIdx.x * blockDim.x + threadIdx.x;
    if (i < n_words) bitmap[i] = 0u;
    if (i == 0) *live_count = 0;
}

// Mark agg0 rows actually referenced by hop1.
__global__ void gafm_bitmap_mark(const int* __restrict__ nbr1_idx,
                                 unsigned int* __restrict__ bitmap, int n) {
    int i = blockIdx.x * blockDim.x + threadIdx.x;
    if (i < n) {
        int j = nbr1_idx[i];
        atomicOr(&bitmap[j >> 5], 1u << (j & 31));
    }
}

// Compact live row IDs: one atomic per wave (ballot + prefix). Order across
// waves is nondeterministic but each live row appears exactly once, and hop0
// writes row-private output -> final result is deterministic.
__global__ void gafm_compact(const unsigned int* __restrict__ bitmap,
                             int* __restrict__ live_rows,
                             int* __restrict__ live_count, int n0) {
    int i = blockIdx.x * blockDim.x + threadIdx.x;
    int lane = threadIdx.x & 63;
    bool live = (i < n0) && ((bitmap[i >> 5] >> (i & 31)) & 1u);
    unsigned long long mask = __ballot(live);
    int base = 0;
    if (lane == 0 && mask) base = atomicAdd(live_count, __popcll(mask));
    base = __shfl(base, 0, 64);
    if (live) {
        int pre = __popcll(mask & ((1ull << lane) - 1ull));
        live_rows[base + pre] = i;
    }
}

// Hop 0 over compacted live rows: 4 rows per wave; 16 lanes per row-group,
// each lane owns a float4. Full waves -> max outstanding-gather density.
__global__ __launch_bounds__(256) void gafm_hop0(
    const float4* __restrict__ emb4,      // entity_emb as [N_ENT][16] float4
    const int*    __restrict__ node_ids0,
    const int*    __restrict__ nbr0,
    const int*    __restrict__ live_rows,
    const int*    __restrict__ live_count,
    float4*       __restrict__ agg0_4)    // [N0][16] float4
{
    const int lane = threadIdx.x & 63;
    const int wave_in_blk = threadIdx.x >> 6;
    const int c   = lane & 15;            // chunk: covers k = 4c..4c+3
    const int g16 = lane & 48;            // base lane of this 16-lane row-group
    const int g   = blockIdx.x * 16 + wave_in_blk * 4 + (lane >> 4);
    if (g >= *live_count) return;         // trailing groups/blocks exit fast
    const int row = live_rows[g];

    // Lane j of the group holds neighbor indices 2j and 2j+1 (coalesced 8B).
    const int2 my_idx = ((const int2*)(nbr0 + (size_t)row * DEG))[c];

    float Sx = 0.f, Sy = 0.f, Sz = 0.f, Sw = 0.f;
    float Qx = 0.f, Qy = 0.f, Qz = 0.f, Qw = 0.f;

    #pragma unroll
    for (int b = 0; b < DEG / 8; ++b) {
        float4 buf[8];
        #pragma unroll
        for (int t = 0; t < 8; ++t) {
            const int d = b * 8 + t;
            const int src = g16 | (d >> 1);                 // stays in-group
            const int idx = __shfl((d & 1) ? my_idx.y : my_idx.x, src, 64);
            buf[t] = emb4[(size_t)idx * 16 + c];
        }
        #pragma unroll
        for (int t = 0; t < 8; ++t) {
            float4 v = buf[t];
            float n2 = fmaf(v.x, v.x, fmaf(v.y, v.y, fmaf(v.z, v.z, v.w * v.w)));
            n2 = group16_sum(n2);
            float r = renorm_scale(n2);
            float ex = v.x * r, ey = v.y * r, ez = v.z * r, ew = v.w * r;
            Sx += ex; Sy += ey; Sz += ez; Sw += ew;
            Qx = fmaf(ex, ex, Qx); Qy = fmaf(ey, ey, Qy);
            Qz = fmaf(ez, ez, Qz); Qw = fmaf(ew, ew, Qw);
        }
    }

    int tidx = node_ids0[row];
    float4 t = emb4[(size_t)tidx * 16 + c];
    float tn2 = fmaf(t.x, t.x, fmaf(t.y, t.y, fmaf(t.z, t.z, t.w * t.w)));
    tn2 = group16_sum(tn2);
    float tr = renorm_scale(tn2);

    float4 o;
    o.x = fmaf(Sx, Sx, -Qx) + t.x * tr;
    o.y = fmaf(Sy, Sy, -Qy) + t.y * tr;
    o.z = fmaf(Sz, Sz, -Qz) + t.z * tr;
    o.w = fmaf(Sw, Sw, -Qw) + t.w * tr;
    agg0_4[(size_t)row * 16 + c] = o;
}

// Hop 1 + score: one wave per batch row (lane = k). 2048 rows -> negligible.
__global__ __launch_bounds__(256) void gafm_hop1(
    const float* __restrict__ entity_emb,
    const float* __restrict__ user_emb,
    const int*   __restrict__ u_ids,
    const int*   __restrict__ item_ids,
    const int*   __restrict__ nbr1_idx,
    const float* __restrict__ agg0,
    float*       __restrict__ out,
    int nb_rows)
{
    int wave = (int)((blockIdx.x * blockDim.x + threadIdx.x) >> 6);
    int lane = threadIdx.x & 63;
    if (wave >= nb_rows) return;

    const int* nb = nbr1_idx + (size_t)wave * DEG;
    float S = 0.0f, Q = 0.0f;
    #pragma unroll 8
    for (int d = 0; d < DEG; ++d) {
        int j = nb[d];
        float e = agg0[(size_t)j * K_DIM + lane];  // plain gather, NO renorm
        S += e;
        Q = fmaf(e, e, Q);
    }
    float agg1 = fmaf(S, S, -Q);

    int ti = item_ids[wave];
    float t = entity_emb[(size_t)ti * K_DIM + lane];
    t *= renorm_scale(wave_sum(t * t));
    float items = agg1 + t;

    int ui = u_ids[wave];
    float uu = user_emb[(size_t)ui * K_DIM + lane];
    uu *= renorm_scale(wave_sum(uu * uu));

    float dot = wave_sum(uu * items);
    if (lane == 0)
        out[wave] = 1.0f / (1.0f + expf(-dot));
}

extern "C" void kernel_launch(void* const* d_in, const int* in_sizes, int n_in,
                              void* d_out, int out_size, void* d_ws, size_t ws_size,
                              hipStream_t stream) {
    // 0 entity_emb [1e6,64] f32   1 user_emb [1e5,64] f32
    // 2..5 Wa/ba/Wh/bh (DEAD: softmax over singleton axis == ones)
    // 6 u [B] i32   7 item_ids [B] i32   8 nbr1_idx [B,32] i32
    // 9 node_ids0 [N0] i32   10 nbr0 [N0,32] i32
    const float* entity_emb = (const float*)d_in[0];
    const float* user_emb   = (const float*)d_in[1];
    const int*   u_ids      = (const int*)d_in[6];
    const int*   item_ids   = (const int*)d_in[7];
    const int*   nbr1_idx   = (const int*)d_in[8];
    const int*   node_ids0  = (const int*)d_in[9];
    const int*   nbr0       = (const int*)d_in[10];
    float*       out        = (float*)d_out;

    const int B   = in_sizes[6];   // 2048
    const int N0  = in_sizes[9];   // 65536
    const int NB1 = in_sizes[8];   // B*DEG = 65536

    // ws layout: agg0 (16MB) | bitmap (8KB) | live_count (4B) | live_rows (256KB)
    float* agg0 = (float*)d_ws;
    const size_t agg0_bytes = (size_t)N0 * K_DIM * sizeof(float);
    const int n_words = (N0 + 31) / 32;
    unsigned int* bitmap   = (unsigned int*)((char*)d_ws + agg0_bytes);
    int* live_count        = (int*)(bitmap + n_words);
    int* live_rows         = live_count + 1;

    gafm_bitmap_zero<<<(n_words + 255) / 256, 256, 0, stream>>>(bitmap, n_words, live_count);
    gafm_bitmap_mark<<<(NB1 + 255) / 256, 256, 0, stream>>>(nbr1_idx, bitmap, NB1);
    gafm_compact<<<(N0 + 255) / 256, 256, 0, stream>>>(bitmap, live_rows, live_count, N0);

    // hop0 over compacted rows: 16 rows per 256-thread block; launch worst-case
    // grid (live_count <= N0); surplus blocks exit on the count check.
    int blocks0 = (N0 + 15) / 16;
    gafm_hop0<<<blocks0, 256, 0, stream>>>((const float4*)entity_emb, node_ids0,
                                           nbr0, live_rows, live_count,
                                           (float4*)agg0);

    // hop1: one wave per row
    int blocks1 = (B + 3) / 4;
    gafm_hop1<<<blocks1, 256, 0, stream>>>(entity_emb, user_emb, u_ids, item_ids,
                                           nbr1_idx, agg0, out, B);
}

// Round 7
// 75.655 us; speedup vs baseline: 1.2043x; 1.2043x over previous
//
#include <hip/hip_runtime.h>
#include <math.h>

#define K_DIM 64
#define DEG 32

// Sum across each 16-lane row-group using DPP row_ror (pure VALU).
__device__ __forceinline__ float group16_sum(float v) {
    int x;
    x = __builtin_amdgcn_update_dpp(0, __float_as_int(v), 0x121, 0xf, 0xf, true);
    v += __int_as_float(x);
    x = __builtin_amdgcn_update_dpp(0, __float_as_int(v), 0x122, 0xf, 0xf, true);
    v += __int_as_float(x);
    x = __builtin_amdgcn_update_dpp(0, __float_as_int(v), 0x124, 0xf, 0xf, true);
    v += __int_as_float(x);
    x = __builtin_amdgcn_update_dpp(0, __float_as_int(v), 0x128, 0xf, 0xf, true);
    v += __int_as_float(x);
    return v;
}

// nn.Embedding(max_norm=1): scale = min(1, 1/max(||e||,1e-12)).
// rsq(n2) > 1 iff norm < 1; rsq(0)=inf -> min gives 1. Matches reference.
__device__ __forceinline__ float renorm_scale(float n2) {
    return fminf(1.0f, __frsqrt_rn(n2));
}

// Mark agg0 rows actually referenced by hop1 (bitmap pre-zeroed via memset).
__global__ void gafm_bitmap_mark(const int* __restrict__ nbr1_idx,
                                 unsigned int* __restrict__ bitmap, int n) {
    int i = blockIdx.x * blockDim.x + threadIdx.x;
    if (i < n) {
        int j = nbr1_idx[i];
        atomicOr(&bitmap[j >> 5], 1u << (j & 31));
    }
}

// Hop 0: 4 consecutive rows per wave; 16 lanes per row-group, lane owns a
// float4. Rows not referenced by nbr1_idx are skipped (dead output).
// Target row prefetched before the neighbor loop (independent -> latency
// hides under the gather stream).
__global__ __launch_bounds__(256) void gafm_hop0(
    const float4* __restrict__ emb4,      // entity_emb as [N_ENT][16] float4
    const int*    __restrict__ node_ids0,
    const int*    __restrict__ nbr0,
    const unsigned int* __restrict__ bitmap,
    float4*       __restrict__ agg0_4,    // [N0][16] float4
    int n0)
{
    const int lane = threadIdx.x & 63;
    const int wave_in_blk = threadIdx.x >> 6;
    const int c   = lane & 15;            // chunk: covers k = 4c..4c+3
    const int g16 = lane & 48;            // base lane of this 16-lane row-group
    const int row = blockIdx.x * 16 + wave_in_blk * 4 + (lane >> 4);
    if (row >= n0) return;
    if (!((bitmap[row >> 5] >> (row & 31)) & 1u)) return;   // dead row

    // Lane j of the group holds neighbor indices 2j and 2j+1 (coalesced 8B).
    const int2 my_idx = ((const int2*)(nbr0 + (size_t)row * DEG))[c];

    // Prefetch the (independent) target row early.
    int tidx = node_ids0[row];
    float4 t = emb4[(size_t)tidx * 16 + c];

    float Sx = 0.f, Sy = 0.f, Sz = 0.f, Sw = 0.f;
    float Qx = 0.f, Qy = 0.f, Qz = 0.f, Qw = 0.f;

    #pragma unroll
    for (int b = 0; b < DEG / 8; ++b) {
        float4 buf[8];
        #pragma unroll
        for (int tt = 0; tt < 8; ++tt) {
            const int d = b * 8 + tt;
            const int src = g16 | (d >> 1);                 // stays in-group
            const int idx = __shfl((d & 1) ? my_idx.y : my_idx.x, src, 64);
            buf[tt] = emb4[(size_t)idx * 16 + c];
        }
        #pragma unroll
        for (int tt = 0; tt < 8; ++tt) {
            float4 v = buf[tt];
            float n2 = fmaf(v.x, v.x, fmaf(v.y, v.y, fmaf(v.z, v.z, v.w * v.w)));
            n2 = group16_sum(n2);
            float r = renorm_scale(n2);
            float ex = v.x * r, ey = v.y * r, ez = v.z * r, ew = v.w * r;
            Sx += ex; Sy += ey; Sz += ez; Sw += ew;
            Qx = fmaf(ex, ex, Qx); Qy = fmaf(ey, ey, Qy);
            Qz = fmaf(ez, ez, Qz); Qw = fmaf(ew, ew, Qw);
        }
    }

    float tn2 = fmaf(t.x, t.x, fmaf(t.y, t.y, fmaf(t.z, t.z, t.w * t.w)));
    tn2 = group16_sum(tn2);
    float tr = renorm_scale(tn2);

    float4 o;
    o.x = fmaf(Sx, Sx, -Qx) + t.x * tr;
    o.y = fmaf(Sy, Sy, -Qy) + t.y * tr;
    o.z = fmaf(Sz, Sz, -Qz) + t.z * tr;
    o.w = fmaf(Sw, Sw, -Qw) + t.w * tr;
    agg0_4[(size_t)row * 16 + c] = o;
}

// Hop 1 + score, same 16-lane/float4 structure: 4 batch rows per wave.
__global__ __launch_bounds__(256) void gafm_hop1(
    const float4* __restrict__ emb4,
    const float4* __restrict__ user4,
    const int*    __restrict__ u_ids,
    const int*    __restrict__ item_ids,
    const int*    __restrict__ nbr1_idx,
    const float4* __restrict__ agg0_4,
    float*        __restrict__ out,
    int nb_rows)
{
    const int lane = threadIdx.x & 63;
    const int wave_in_blk = threadIdx.x >> 6;
    const int c   = lane & 15;
    const int g16 = lane & 48;
    const int row = blockIdx.x * 16 + wave_in_blk * 4 + (lane >> 4);
    if (row >= nb_rows) return;

    const int2 my_idx = ((const int2*)(nbr1_idx + (size_t)row * DEG))[c];

    // Prefetch independent item/user rows early.
    int ti = item_ids[row];
    int ui = u_ids[row];
    float4 t  = emb4[(size_t)ti * 16 + c];
    float4 uu = user4[(size_t)ui * 16 + c];

    float Sx = 0.f, Sy = 0.f, Sz = 0.f, Sw = 0.f;
    float Qx = 0.f, Qy = 0.f, Qz = 0.f, Qw = 0.f;

    #pragma unroll
    for (int b = 0; b < DEG / 8; ++b) {
        float4 buf[8];
        #pragma unroll
        for (int tt = 0; tt < 8; ++tt) {
            const int d = b * 8 + tt;
            const int src = g16 | (d >> 1);
            const int idx = __shfl((d & 1) ? my_idx.y : my_idx.x, src, 64);
            buf[tt] = agg0_4[(size_t)idx * 16 + c];   // plain gather, NO renorm
        }
        #pragma unroll
        for (int tt = 0; tt < 8; ++tt) {
            float4 v = buf[tt];
            Sx += v.x; Sy += v.y; Sz += v.z; Sw += v.w;
            Qx = fmaf(v.x, v.x, Qx); Qy = fmaf(v.y, v.y, Qy);
            Qz = fmaf(v.z, v.z, Qz); Qw = fmaf(v.w, v.w, Qw);
        }
    }

    float tn2 = fmaf(t.x, t.x, fmaf(t.y, t.y, fmaf(t.z, t.z, t.w * t.w)));
    float tr = renorm_scale(group16_sum(tn2));
    float un2 = fmaf(uu.x, uu.x, fmaf(uu.y, uu.y, fmaf(uu.z, uu.z, uu.w * uu.w)));
    float ur = renorm_scale(group16_sum(un2));

    float ix = fmaf(Sx, Sx, -Qx) + t.x * tr;
    float iy = fmaf(Sy, Sy, -Qy) + t.y * tr;
    float iz = fmaf(Sz, Sz, -Qz) + t.z * tr;
    float iw = fmaf(Sw, Sw, -Qw) + t.w * tr;

    float d4 = uu.x * ix;
    d4 = fmaf(uu.y, iy, d4);
    d4 = fmaf(uu.z, iz, d4);
    d4 = fmaf(uu.w, iw, d4);
    float dot = group16_sum(d4) * ur;

    if (c == 0)
        out[row] = 1.0f / (1.0f + expf(-dot));
}

extern "C" void kernel_launch(void* const* d_in, const int* in_sizes, int n_in,
                              void* d_out, int out_size, void* d_ws, size_t ws_size,
                              hipStream_t stream) {
    // 0 entity_emb [1e6,64] f32   1 user_emb [1e5,64] f32
    // 2..5 Wa/ba/Wh/bh (DEAD: softmax over singleton axis == ones)
    // 6 u [B] i32   7 item_ids [B] i32   8 nbr1_idx [B,32] i32
    // 9 node_ids0 [N0] i32   10 nbr0 [N0,32] i32
    const float* entity_emb = (const float*)d_in[0];
    const float* user_emb   = (const float*)d_in[1];
    const int*   u_ids      = (const int*)d_in[6];
    const int*   item_ids   = (const int*)d_in[7];
    const int*   nbr1_idx   = (const int*)d_in[8];
    const int*   node_ids0  = (const int*)d_in[9];
    const int*   nbr0       = (const int*)d_in[10];
    float*       out        = (float*)d_out;

    const int B   = in_sizes[6];   // 2048
    const int N0  = in_sizes[9];   // 65536
    const int NB1 = in_sizes[8];   // B*DEG = 65536

    // ws layout: agg0 (16MB) | bitmap (8KB)
    float* agg0 = (float*)d_ws;
    const size_t agg0_bytes = (size_t)N0 * K_DIM * sizeof(float);
    const int n_words = (N0 + 31) / 32;
    unsigned int* bitmap = (unsigned int*)((char*)d_ws + agg0_bytes);

    // Zero bitmap via memset node (graph-capturable), then mark live rows.
    hipMemsetAsync(bitmap, 0, (size_t)n_words * 4, stream);
    gafm_bitmap_mark<<<(NB1 + 255) / 256, 256, 0, stream>>>(nbr1_idx, bitmap, NB1);

    // hop0: 16 consecutive rows per 256-thread block (4 waves x 4 rows)
    int blocks0 = (N0 + 15) / 16;
    gafm_hop0<<<blocks0, 256, 0, stream>>>((const float4*)entity_emb, node_ids0,
                                           nbr0, bitmap, (float4*)agg0, N0);

    // hop1: 16 rows per block
    int blocks1 = (B + 15) / 16;
    gafm_hop1<<<blocks1, 256, 0, stream>>>((const float4*)entity_emb,
                                           (const float4*)user_emb,
                                           u_ids, item_ids, nbr1_idx,
                                           (const float4*)agg0, out, B);
}